// Round 4
// baseline (98.972 us; speedup 1.0000x reference)
//
#include <hip/hip_runtime.h>

typedef __attribute__((ext_vector_type(4))) float f32x4;
typedef __attribute__((ext_vector_type(16))) float f32x16;
typedef __attribute__((ext_vector_type(8))) __bf16 bf16x8;
typedef __attribute__((ext_vector_type(4))) __bf16 bf16x4;

#define L_SEQ 1024
#define NB 8
#define EMB 256
#define NHEAD 8
#define HD 32
#define MROWS 8192  // L_SEQ * NB

static __device__ __forceinline__ f32x4 mfma_bf16(bf16x8 a, bf16x8 b, f32x4 c) {
    return __builtin_amdgcn_mfma_f32_16x16x32_bf16(a, b, c, 0, 0, 0);
}
static __device__ __forceinline__ f32x16 mfma32(bf16x8 a, bf16x8 b, f32x16 c) {
    return __builtin_amdgcn_mfma_f32_32x32x16_bf16(a, b, c, 0, 0, 0);
}

static __device__ __forceinline__ unsigned pack2(float a, float b) {
    union { __bf16 h; unsigned short u; } lo, hi;
    lo.h = (__bf16)a; hi.h = (__bf16)b;
    return (unsigned)lo.u | ((unsigned)hi.u << 16);
}

// v_permlane32_swap_b32: a.hi32 <-> b.lo32.
// After: a = {a.lo(old), b.lo(old from lane-32)}, b = {a.hi(old from lane+32), b.hi(old)}.
static __device__ __forceinline__ void permswap(unsigned &a, unsigned &b) {
    asm("v_permlane32_swap_b32 %0, %1" : "+v"(a), "+v"(b));
}

struct GemmBatch {
    const void* X[6];
    const float* W[6];
    const float* Bv[6];
    void* O[6];
    float scale[6];
};

// C[m,n] = (sum_k X[m,k] * W[n,k] + bias[n]) * scale
// BM=128, BN=64, BK=64, 256 threads = 4 waves (2x2), each wave 64x32 via 4x2 16x16 frags.
template<bool X_BF16, bool OUT_F32>
__global__ __launch_bounds__(256, 2)
void gemm_kernel(GemmBatch batch) {
    __shared__ __bf16 Xl[128][72];
    __shared__ __bf16 Wl[64][72];
    const int z = blockIdx.z;
    const int fid = blockIdx.x;
    const int swz = (fid & 7) * 32 + (fid >> 3);   // 256 blocks -> 8 XCD chunks of 32
    const int nblk = swz & 3, mblk = swz >> 2;
    const float* __restrict__ W = batch.W[z];
    const float* __restrict__ bias = batch.Bv[z];
    const float scale = batch.scale[z];
    const int tid = threadIdx.x;
    const int w = tid >> 6, lane = tid & 63;
    const int g = lane >> 4, li = lane & 15;
    const int wr = w >> 1, wc = w & 1;

    f32x4 acc[4][2];
#pragma unroll
    for (int i = 0; i < 4; ++i)
#pragma unroll
        for (int j = 0; j < 2; ++j) acc[i][j] = f32x4{0.f, 0.f, 0.f, 0.f};

    for (int kk = 0; kk < 4; ++kk) {
        __syncthreads();
        if (X_BF16) {
            const __bf16* Xb = (const __bf16*)batch.X[z];
#pragma unroll
            for (int p = 0; p < 4; ++p) {
                int idx = tid + p * 256;
                int row = idx >> 3, c8 = (idx & 7) * 8;
                bf16x8 xv = *(const bf16x8*)(Xb + (size_t)(mblk * 128 + row) * 256 + kk * 64 + c8);
                *(bf16x8*)&Xl[row][c8] = xv;
            }
        } else {
            const float* Xf = (const float*)batch.X[z];
#pragma unroll
            for (int p = 0; p < 8; ++p) {
                int idx = tid + p * 256;
                int row = idx >> 4, c4 = (idx & 15) * 4;
                f32x4 xv = *(const f32x4*)(Xf + (size_t)(mblk * 128 + row) * 256 + kk * 64 + c4);
                bf16x4 bv;
#pragma unroll
                for (int j = 0; j < 4; ++j) bv[j] = (__bf16)xv[j];
                *(bf16x4*)&Xl[row][c4] = bv;
            }
        }
#pragma unroll
        for (int p = 0; p < 4; ++p) {
            int idx = tid + p * 256;
            int row = idx >> 4, c4 = (idx & 15) * 4;
            f32x4 wv = *(const f32x4*)(W + (size_t)(nblk * 64 + row) * 256 + kk * 64 + c4);
            bf16x4 bv;
#pragma unroll
            for (int j = 0; j < 4; ++j) bv[j] = (__bf16)wv[j];
            *(bf16x4*)&Wl[row][c4] = bv;
        }
        __syncthreads();
#pragma unroll
        for (int ks = 0; ks < 2; ++ks) {
            bf16x8 a[4], b[2];
#pragma unroll
            for (int af = 0; af < 4; ++af)
                a[af] = *(const bf16x8*)&Xl[wr * 64 + af * 16 + li][ks * 32 + g * 8];
#pragma unroll
            for (int bi = 0; bi < 2; ++bi)
                b[bi] = *(const bf16x8*)&Wl[wc * 32 + bi * 16 + li][ks * 32 + g * 8];
#pragma unroll
            for (int af = 0; af < 4; ++af)
#pragma unroll
                for (int bi = 0; bi < 2; ++bi)
                    acc[af][bi] = mfma_bf16(a[af], b[bi], acc[af][bi]);
        }
    }
#pragma unroll
    for (int af = 0; af < 4; ++af)
#pragma unroll
        for (int bi = 0; bi < 2; ++bi)
#pragma unroll
            for (int r = 0; r < 4; ++r) {
                int mrow = mblk * 128 + wr * 64 + af * 16 + 4 * g + r;
                int ncol = nblk * 64 + wc * 32 + bi * 16 + li;
                float v = (acc[af][bi][r] + bias[ncol]) * scale;
                if (OUT_F32)
                    ((float*)batch.O[z])[(size_t)mrow * 256 + ncol] = v;
                else
                    ((__bf16*)batch.O[z])[(size_t)mrow * 256 + ncol] = (__bf16)v;
            }
}

struct AttnArgs {
    const __bf16* Q[2];
    const __bf16* K[2];
    const __bf16* V[2];
    __bf16* AO[2];
};

// Swapped-QK^T flash attention, fixed-shift softmax (no online max).
// 2-wave blocks (64 q rows each) -> 8 independent blocks/CU (LDS-capped), so
// staging-latency stalls hide across blocks. P half-swap via v_permlane32_swap.
// Q pre-scaled by (1/sqrt(hd))*log2(e); QK C-init = -12 (loop-invariant), p = exp2(s).
// Row sums accumulated via MFMA with a ones B-operand; epilogue shuffle-free.
__global__ __launch_bounds__(128, 4)
void attn_kernel(AttnArgs args) {
    __shared__ __bf16 Kl[128][40];   // K tile [s][d], padded
    __shared__ __bf16 Vt[32][136];   // V^T tile [d][s], padded + XOR-swizzled cols
    const int fid = blockIdx.x;
    const int swz = (fid & 7) * 256 + (fid >> 3);  // 2048 blocks -> 8 XCD chunks of 256
    const int qb = swz & 15;
    const int nh = (swz >> 4) & 63;
    const int st = swz >> 10;
    const int n = nh >> 3, h = nh & 7;
    const __bf16* __restrict__ Q = args.Q[st];
    const __bf16* __restrict__ K = args.K[st];
    const __bf16* __restrict__ V = args.V[st];
    __bf16* __restrict__ AO = args.AO[st];
    const int tid = threadIdx.x;
    const int w = tid >> 6, lane = tid & 63;
    const int q32 = lane & 31, hi = lane >> 5;

    // Q B-fragments: col = q32, k(kb) = kb*16 + 8*hi + e
    bf16x8 qf[2];
    {
        int qrow = qb * 64 + w * 32 + q32;
#pragma unroll
        for (int kb = 0; kb < 2; ++kb)
            qf[kb] = *(const bf16x8*)(Q + ((size_t)qrow * NB + n) * EMB + h * HD + kb * 16 + hi * 8);
    }

    bf16x8 ones;
#pragma unroll
    for (int j = 0; j < 8; ++j) ones[j] = (__bf16)1.0f;
    f32x16 minit;
#pragma unroll
    for (int r = 0; r < 16; ++r) minit[r] = -12.0f;   // fixed softmax shift (loop-invariant C)

    f32x16 accO, accL;
#pragma unroll
    for (int r = 0; r < 16; ++r) { accO[r] = 0.f; accL[r] = 0.f; }

    const int vsw_r = ((q32 >> 3) & 3) << 3;   // read-side Vt column swizzle

    for (int t = 0; t < 8; ++t) {
        const int s0 = t * 128;
        __syncthreads();
#pragma unroll
        for (int p = 0; p < 4; ++p) {
            int idx = tid + p * 128;              // 0..511
            int row = idx >> 2, c8 = (idx & 3) * 8;
            size_t gaddr = ((size_t)(s0 + row) * NB + n) * EMB + h * HD + c8;
            *(bf16x8*)&Kl[row][c8] = *(const bf16x8*)(K + gaddr);
            bf16x8 vv = *(const bf16x8*)(V + gaddr);
#pragma unroll
            for (int j = 0; j < 8; ++j) {
                int d = c8 + j;
                Vt[d][row ^ (((d >> 3) & 3) << 3)] = vv[j];
            }
        }
        __syncthreads();

#pragma unroll
        for (int sb = 0; sb < 4; ++sb) {
            // S^T = K * Q^T - 12 : lane holds col q32, rows (r&3)+8*(r>>2)+4*hi
            bf16x8 kf0 = *(const bf16x8*)&Kl[sb * 32 + q32][hi * 8];
            bf16x8 kf1 = *(const bf16x8*)&Kl[sb * 32 + q32][16 + hi * 8];
            f32x16 s = mfma32(kf0, qf[0], minit);
            s = mfma32(kf1, qf[1], s);
            float p[16];
#pragma unroll
            for (int r = 0; r < 16; ++r) p[r] = exp2f(s[r]);

            // pack P -> bf16 A-fragments; half-swap via v_permlane32_swap_b32
            bf16x8 pa[2];
#pragma unroll
            for (int ks = 0; ks < 2; ++ks) {
                unsigned x0 = pack2(p[8 * ks + 0], p[8 * ks + 1]);
                unsigned x1 = pack2(p[8 * ks + 2], p[8 * ks + 3]);
                unsigned x2 = pack2(p[8 * ks + 4], p[8 * ks + 5]);
                unsigned x3 = pack2(p[8 * ks + 6], p[8 * ks + 7]);
                permswap(x0, x2);   // x0 -> w0, x2 -> w2
                permswap(x1, x3);   // x1 -> w1, x3 -> w3
                union { unsigned u[4]; bf16x8 v; } cvt;
                cvt.u[0] = x0; cvt.u[1] = x1; cvt.u[2] = x2; cvt.u[3] = x3;
                pa[ks] = cvt.v;
            }
            // PV and row-sum accumulation (both in C-layout, rows = q)
#pragma unroll
            for (int ks = 0; ks < 2; ++ks) {
                bf16x8 vf = *(const bf16x8*)&Vt[q32][(sb * 32 + ks * 16 + hi * 8) ^ vsw_r];
                accO = mfma32(pa[ks], vf, accO);
                accL = mfma32(pa[ks], ones, accL);
            }
        }
    }

    // epilogue: out = accO / accL (identical C-layout -> no shuffles)
#pragma unroll
    for (int r = 0; r < 16; ++r) {
        int crow = (r & 3) + 8 * (r >> 2) + 4 * hi;
        int row = qb * 64 + w * 32 + crow;
        AO[((size_t)row * NB + n) * EMB + h * HD + q32] = (__bf16)(accO[r] / accL[r]);
    }
}

extern "C" void kernel_launch(void* const* d_in, const int* in_sizes, int n_in,
                              void* d_out, int out_size, void* d_ws, size_t ws_size,
                              hipStream_t stream) {
    const size_t SZ = (size_t)MROWS * EMB;
    __bf16* wsb = (__bf16*)d_ws;
    __bf16* arr[8];
    for (int i = 0; i < 8; ++i) arr[i] = wsb + (size_t)i * SZ;

    // 1/sqrt(32) * log2(e): fold attention scale + exp2 conversion into Q
    const float qscale = 0.25504310349362475f;

    GemmBatch pb{};
    for (int s = 0; s < 6; ++s) {
        pb.X[s] = d_in[s];
        pb.W[s] = (const float*)d_in[6 + s];
        pb.Bv[s] = (const float*)d_in[14 + s];
        pb.O[s] = arr[s];
        pb.scale[s] = (s == 0 || s == 3) ? qscale : 1.0f;
    }
    hipLaunchKernelGGL((gemm_kernel<false, false>), dim3(256, 1, 6), dim3(256), 0, stream, pb);

    AttnArgs aa;
    aa.Q[0] = arr[0]; aa.K[0] = arr[1]; aa.V[0] = arr[2]; aa.AO[0] = arr[6];
    aa.Q[1] = arr[3]; aa.K[1] = arr[4]; aa.V[1] = arr[5]; aa.AO[1] = arr[7];
    hipLaunchKernelGGL(attn_kernel, dim3(2048), dim3(128), 0, stream, aa);

    GemmBatch ob{};
    for (int s = 0; s < 2; ++s) {
        ob.X[s] = arr[6 + s];
        ob.W[s] = (const float*)d_in[12 + s];
        ob.Bv[s] = (const float*)d_in[20 + s];
        ob.O[s] = (float*)d_out + (size_t)s * SZ;
        ob.scale[s] = 1.0f;
    }
    hipLaunchKernelGGL((gemm_kernel<true, true>), dim3(256, 1, 2), dim3(256), 0, stream, ob);
}

// Round 6
// 94.656 us; speedup vs baseline: 1.0456x; 1.0456x over previous
//
#include <hip/hip_runtime.h>

typedef __attribute__((ext_vector_type(4))) float f32x4;
typedef __attribute__((ext_vector_type(16))) float f32x16;
typedef __attribute__((ext_vector_type(8))) __bf16 bf16x8;
typedef __attribute__((ext_vector_type(4))) __bf16 bf16x4;

#define L_SEQ 1024
#define NB 8
#define EMB 256
#define NHEAD 8
#define HD 32
#define MROWS 8192  // L_SEQ * NB
#define SZ_ELEM ((size_t)MROWS * EMB)

static __device__ __forceinline__ f32x4 mfma_bf16(bf16x8 a, bf16x8 b, f32x4 c) {
    return __builtin_amdgcn_mfma_f32_16x16x32_bf16(a, b, c, 0, 0, 0);
}
static __device__ __forceinline__ f32x16 mfma32(bf16x8 a, bf16x8 b, f32x16 c) {
    return __builtin_amdgcn_mfma_f32_32x32x16_bf16(a, b, c, 0, 0, 0);
}

static __device__ __forceinline__ unsigned pack2(float a, float b) {
    union { __bf16 h; unsigned short u; } lo, hi;
    lo.h = (__bf16)a; hi.h = (__bf16)b;
    return (unsigned)lo.u | ((unsigned)hi.u << 16);
}

// v_permlane32_swap_b32: a.hi-half-lanes <-> b.lo-half-lanes (R4-proven)
static __device__ __forceinline__ void permswap(unsigned &a, unsigned &b) {
    asm("v_permlane32_swap_b32 %0, %1" : "+v"(a), "+v"(b));
}

struct GemmBatch {
    const void* X[6];
    const float* W[6];
    const float* Bv[6];
    void* O[6];
    float scale[6];
    const float* P0[6];   // XMODE==2: s-half-0 partial O (f32)
    const float* P1[6];   // XMODE==2: s-half-1 partial O (f32)
    const float* L0[6];   // XMODE==2: s-half-0 partial row-sum [MROWS][NHEAD]
    const float* L1[6];   // XMODE==2: s-half-1 partial row-sum [MROWS][NHEAD]
};

// C[m,n] = (sum_k X[m,k] * W[n,k] + bias[n]) * scale
// BM=128, BN=64, BK=64, 256 threads = 4 waves (2x2), each wave 64x32.
// XMODE: 0 = f32 X, 1 = bf16 X, 2 = combine two f32 partials (split-s attention).
template<int XMODE, bool OUT_F32>
__global__ __launch_bounds__(256, 2)
void gemm_kernel(GemmBatch batch) {
    __shared__ __bf16 Xl[128][72];
    __shared__ __bf16 Wl[64][72];
    const int z = blockIdx.z;
    const int fid = blockIdx.x;
    const int swz = (fid & 7) * 32 + (fid >> 3);   // 256 blocks -> 8 XCD chunks of 32
    const int nblk = swz & 3, mblk = swz >> 2;
    const float* __restrict__ W = batch.W[z];
    const float* __restrict__ bias = batch.Bv[z];
    const float scale = batch.scale[z];
    const int tid = threadIdx.x;
    const int w = tid >> 6, lane = tid & 63;
    const int g = lane >> 4, li = lane & 15;
    const int wr = w >> 1, wc = w & 1;

    f32x4 acc[4][2];
#pragma unroll
    for (int i = 0; i < 4; ++i)
#pragma unroll
        for (int j = 0; j < 2; ++j) acc[i][j] = f32x4{0.f, 0.f, 0.f, 0.f};

    for (int kk = 0; kk < 4; ++kk) {
        __syncthreads();
        if (XMODE == 1) {
            const __bf16* Xb = (const __bf16*)batch.X[z];
#pragma unroll
            for (int p = 0; p < 4; ++p) {
                int idx = tid + p * 256;
                int row = idx >> 3, c8 = (idx & 7) * 8;
                bf16x8 xv = *(const bf16x8*)(Xb + (size_t)(mblk * 128 + row) * 256 + kk * 64 + c8);
                *(bf16x8*)&Xl[row][c8] = xv;
            }
        } else if (XMODE == 0) {
            const float* Xf = (const float*)batch.X[z];
#pragma unroll
            for (int p = 0; p < 8; ++p) {
                int idx = tid + p * 256;
                int row = idx >> 4, c4 = (idx & 15) * 4;
                f32x4 xv = *(const f32x4*)(Xf + (size_t)(mblk * 128 + row) * 256 + kk * 64 + c4);
                bf16x4 bv;
#pragma unroll
                for (int j = 0; j < 4; ++j) bv[j] = (__bf16)xv[j];
                *(bf16x4*)&Xl[row][c4] = bv;
            }
        } else {  // XMODE == 2: X = (P0+P1) * rcp(L0+L1), per-head denominator
            const float* p0 = batch.P0[z];
            const float* p1 = batch.P1[z];
            const float* l0 = batch.L0[z];
            const float* l1 = batch.L1[z];
#pragma unroll
            for (int p = 0; p < 8; ++p) {
                int idx = tid + p * 256;
                int row = idx >> 4, c4 = (idx & 15) * 4;
                int R = mblk * 128 + row;
                int hcol = (kk * 64 + c4) >> 5;        // head of this column group
                size_t off = (size_t)R * 256 + kk * 64 + c4;
                f32x4 a = *(const f32x4*)(p0 + off);
                f32x4 b = *(const f32x4*)(p1 + off);
                float rinv = __builtin_amdgcn_rcpf(l0[R * NHEAD + hcol] + l1[R * NHEAD + hcol]);
                bf16x4 bv;
#pragma unroll
                for (int j = 0; j < 4; ++j) bv[j] = (__bf16)((a[j] + b[j]) * rinv);
                *(bf16x4*)&Xl[row][c4] = bv;
            }
        }
#pragma unroll
        for (int p = 0; p < 4; ++p) {
            int idx = tid + p * 256;
            int row = idx >> 4, c4 = (idx & 15) * 4;
            f32x4 wv = *(const f32x4*)(W + (size_t)(nblk * 64 + row) * 256 + kk * 64 + c4);
            bf16x4 bv;
#pragma unroll
            for (int j = 0; j < 4; ++j) bv[j] = (__bf16)wv[j];
            *(bf16x4*)&Wl[row][c4] = bv;
        }
        __syncthreads();
#pragma unroll
        for (int ks = 0; ks < 2; ++ks) {
            bf16x8 a[4], b[2];
#pragma unroll
            for (int af = 0; af < 4; ++af)
                a[af] = *(const bf16x8*)&Xl[wr * 64 + af * 16 + li][ks * 32 + g * 8];
#pragma unroll
            for (int bi = 0; bi < 2; ++bi)
                b[bi] = *(const bf16x8*)&Wl[wc * 32 + bi * 16 + li][ks * 32 + g * 8];
#pragma unroll
            for (int af = 0; af < 4; ++af)
#pragma unroll
                for (int bi = 0; bi < 2; ++bi)
                    acc[af][bi] = mfma_bf16(a[af], b[bi], acc[af][bi]);
        }
    }
#pragma unroll
    for (int af = 0; af < 4; ++af)
#pragma unroll
        for (int bi = 0; bi < 2; ++bi)
#pragma unroll
            for (int r = 0; r < 4; ++r) {
                int mrow = mblk * 128 + wr * 64 + af * 16 + 4 * g + r;
                int ncol = nblk * 64 + wc * 32 + bi * 16 + li;
                float v = (acc[af][bi][r] + bias[ncol]) * scale;
                if (OUT_F32)
                    ((float*)batch.O[z])[(size_t)mrow * 256 + ncol] = v;
                else
                    ((__bf16*)batch.O[z])[(size_t)mrow * 256 + ncol] = (__bf16)v;
            }
}

struct AttnArgs {
    const __bf16* Q[2];
    const __bf16* K[2];
    const __bf16* V[2];
    __bf16* AO[2];
    float* pO;    // SPLIT: partial O, [st][half][8192][256] f32
    float* pL;    // SPLIT: partial row-sum, [st][half][8192][NHEAD] f32
};

// Swapped-QK^T flash attention, fixed-shift softmax (no online max).
// Q pre-scaled by (1/sqrt(hd))*log2(e); QK C-init = -12, p = exp2(s).
// Row sums via MFMA with ones B-operand.
// SPLIT: s-dimension split x2 across blocks (pure-sum partials -> fp32 partial
// out + per-head row-sum; combined in the out-projection's staging). Doubles
// grid -> 8 blocks/CU (occupancy was grid-limited at 31%).
template<bool SPLIT>
__global__ __launch_bounds__(256, 4)
void attn_kernel(AttnArgs args) {
    __shared__ __bf16 Kl[128][40];   // K tile [s][d], padded
    __shared__ __bf16 Vt[32][136];   // V^T tile [d][s], padded + XOR-swizzled cols
    const int fid = blockIdx.x;
    int qb, nh, st, half, t0;
    if (SPLIT) {
        const int swz = (fid & 7) * 256 + (fid >> 3);  // 2048 -> 8 XCD chunks of 256
        qb = swz & 7;
        half = (swz >> 3) & 1;
        nh = (swz >> 4) & 63;
        st = swz >> 10;
        t0 = half * 4;
    } else {
        const int swz = (fid & 7) * 128 + (fid >> 3);  // 1024 -> 8 XCD chunks of 128
        qb = swz & 7;
        nh = (swz >> 3) & 63;
        st = swz >> 9;
        half = 0;
        t0 = 0;
    }
    const int n = nh >> 3, h = nh & 7;
    const __bf16* __restrict__ Q = args.Q[st];
    const __bf16* __restrict__ K = args.K[st];
    const __bf16* __restrict__ V = args.V[st];
    const int tid = threadIdx.x;
    const int w = tid >> 6, lane = tid & 63;
    const int q32 = lane & 31, hi = lane >> 5;

    // Q B-fragments: col = q32, k(kb) = kb*16 + 8*hi + e
    bf16x8 qf[2];
    {
        int qrow = qb * 128 + w * 32 + q32;
#pragma unroll
        for (int kb = 0; kb < 2; ++kb)
            qf[kb] = *(const bf16x8*)(Q + ((size_t)qrow * NB + n) * EMB + h * HD + kb * 16 + hi * 8);
    }

    bf16x8 ones;
#pragma unroll
    for (int j = 0; j < 8; ++j) ones[j] = (__bf16)1.0f;

    f32x16 accO, accL;
#pragma unroll
    for (int r = 0; r < 16; ++r) { accO[r] = 0.f; accL[r] = 0.f; }

    const int vsw_r = ((q32 >> 3) & 3) << 3;   // read-side Vt column swizzle

    const int NT = SPLIT ? 4 : 8;
    for (int tt = 0; tt < NT; ++tt) {
        const int s0 = (t0 + tt) * 128;
        __syncthreads();
#pragma unroll
        for (int p = 0; p < 2; ++p) {
            int idx = tid + p * 256;              // 0..511
            int row = idx >> 2, c8 = (idx & 3) * 8;
            size_t gaddr = ((size_t)(s0 + row) * NB + n) * EMB + h * HD + c8;
            *(bf16x8*)&Kl[row][c8] = *(const bf16x8*)(K + gaddr);
            bf16x8 vv = *(const bf16x8*)(V + gaddr);
#pragma unroll
            for (int j = 0; j < 8; ++j) {
                int d = c8 + j;
                Vt[d][row ^ (((d >> 3) & 3) << 3)] = vv[j];
            }
        }
        __syncthreads();

#pragma unroll
        for (int sb = 0; sb < 4; ++sb) {
            // S^T = K * Q^T - 12 : lane holds col q32, rows (r&3)+8*(r>>2)+4*hi
            bf16x8 kf0 = *(const bf16x8*)&Kl[sb * 32 + q32][hi * 8];
            bf16x8 kf1 = *(const bf16x8*)&Kl[sb * 32 + q32][16 + hi * 8];
            f32x16 s;
#pragma unroll
            for (int r = 0; r < 16; ++r) s[r] = -12.0f;   // fixed softmax shift
            __builtin_amdgcn_s_setprio(1);
            s = mfma32(kf0, qf[0], s);
            s = mfma32(kf1, qf[1], s);
            __builtin_amdgcn_s_setprio(0);
            float p[16];
#pragma unroll
            for (int r = 0; r < 16; ++r) p[r] = exp2f(s[r]);

            // pack P -> bf16 A-fragments; half-swap via v_permlane32_swap_b32
            bf16x8 pa[2];
#pragma unroll
            for (int ks = 0; ks < 2; ++ks) {
                unsigned x0 = pack2(p[8 * ks + 0], p[8 * ks + 1]);
                unsigned x1 = pack2(p[8 * ks + 2], p[8 * ks + 3]);
                unsigned x2 = pack2(p[8 * ks + 4], p[8 * ks + 5]);
                unsigned x3 = pack2(p[8 * ks + 6], p[8 * ks + 7]);
                permswap(x0, x2);
                permswap(x1, x3);
                union { unsigned u[4]; bf16x8 v; } cvt;
                cvt.u[0] = x0; cvt.u[1] = x1; cvt.u[2] = x2; cvt.u[3] = x3;
                pa[ks] = cvt.v;
            }
            // PV and row-sum accumulation (both in C-layout, rows = q, cols = d)
            bf16x8 vf0 = *(const bf16x8*)&Vt[q32][(sb * 32 + hi * 8) ^ vsw_r];
            bf16x8 vf1 = *(const bf16x8*)&Vt[q32][(sb * 32 + 16 + hi * 8) ^ vsw_r];
            __builtin_amdgcn_s_setprio(1);
            accO = mfma32(pa[0], vf0, accO);
            accL = mfma32(pa[0], ones, accL);
            accO = mfma32(pa[1], vf1, accO);
            accL = mfma32(pa[1], ones, accL);
            __builtin_amdgcn_s_setprio(0);
        }
    }

    if (SPLIT) {
        float* po = args.pO + (size_t)(st * 2 + half) * SZ_ELEM;
        float* pl = args.pL + (size_t)(st * 2 + half) * MROWS * NHEAD;
#pragma unroll
        for (int r = 0; r < 16; ++r) {
            int crow = (r & 3) + 8 * (r >> 2) + 4 * hi;
            int row = qb * 128 + w * 32 + crow;
            po[((size_t)row * NB + n) * EMB + h * HD + q32] = accO[r];
        }
        if (q32 == 0) {
#pragma unroll
            for (int r = 0; r < 16; ++r) {
                int crow = (r & 3) + 8 * (r >> 2) + 4 * hi;
                int row = qb * 128 + w * 32 + crow;
                pl[((size_t)row * NB + n) * NHEAD + h] = accL[r];
            }
        }
    } else {
        __bf16* __restrict__ AO = args.AO[st];
#pragma unroll
        for (int r = 0; r < 16; ++r) {
            int crow = (r & 3) + 8 * (r >> 2) + 4 * hi;
            int row = qb * 128 + w * 32 + crow;
            AO[((size_t)row * NB + n) * EMB + h * HD + q32] = (__bf16)(accO[r] / accL[r]);
        }
    }
}

extern "C" void kernel_launch(void* const* d_in, const int* in_sizes, int n_in,
                              void* d_out, int out_size, void* d_ws, size_t ws_size,
                              hipStream_t stream) {
    const size_t SZ = SZ_ELEM;
    __bf16* wsb = (__bf16*)d_ws;
    __bf16* arr[8];
    for (int i = 0; i < 8; ++i) arr[i] = wsb + (size_t)i * SZ;
    // Split layout: [0..6*SZ bf16: QKV x2] [pO: 4*SZ f32] [pL: 4*MROWS*NHEAD f32]
    float* pO = (float*)(wsb + 6 * SZ);
    float* pL = pO + 4 * SZ;
    const size_t need = 6 * SZ * 2 + 4 * SZ * 4 + 4 * (size_t)MROWS * NHEAD * 4;
    const bool split = ws_size >= need;

    // 1/sqrt(32) * log2(e): fold attention scale + exp2 conversion into Q
    const float qscale = 0.25504310349362475f;

    GemmBatch pb{};
    for (int s = 0; s < 6; ++s) {
        pb.X[s] = d_in[s];
        pb.W[s] = (const float*)d_in[6 + s];
        pb.Bv[s] = (const float*)d_in[14 + s];
        pb.O[s] = arr[s];
        pb.scale[s] = (s == 0 || s == 3) ? qscale : 1.0f;
    }
    hipLaunchKernelGGL((gemm_kernel<0, false>), dim3(256, 1, 6), dim3(256), 0, stream, pb);

    AttnArgs aa{};
    aa.Q[0] = arr[0]; aa.K[0] = arr[1]; aa.V[0] = arr[2]; aa.AO[0] = arr[6];
    aa.Q[1] = arr[3]; aa.K[1] = arr[4]; aa.V[1] = arr[5]; aa.AO[1] = arr[7];
    aa.pO = pO; aa.pL = pL;
    if (split)
        hipLaunchKernelGGL(attn_kernel<true>, dim3(2048), dim3(256), 0, stream, aa);
    else
        hipLaunchKernelGGL(attn_kernel<false>, dim3(1024), dim3(256), 0, stream, aa);

    GemmBatch ob{};
    for (int s = 0; s < 2; ++s) {
        ob.X[s] = arr[6 + s];
        ob.W[s] = (const float*)d_in[12 + s];
        ob.Bv[s] = (const float*)d_in[20 + s];
        ob.O[s] = (float*)d_out + (size_t)s * SZ;
        ob.scale[s] = 1.0f;
        ob.P0[s] = pO + (size_t)(s * 2 + 0) * SZ;
        ob.P1[s] = pO + (size_t)(s * 2 + 1) * SZ;
        ob.L0[s] = pL + (size_t)(s * 2 + 0) * MROWS * NHEAD;
        ob.L1[s] = pL + (size_t)(s * 2 + 1) * MROWS * NHEAD;
    }
    if (split)
        hipLaunchKernelGGL((gemm_kernel<2, true>), dim3(256, 1, 2), dim3(256), 0, stream, ob);
    else
        hipLaunchKernelGGL((gemm_kernel<1, true>), dim3(256, 1, 2), dim3(256), 0, stream, ob);
}

// Round 8
// 73.807 us; speedup vs baseline: 1.3410x; 1.2825x over previous
//
#include <hip/hip_runtime.h>

typedef __attribute__((ext_vector_type(4))) float f32x4;
typedef __attribute__((ext_vector_type(16))) float f32x16;
typedef __attribute__((ext_vector_type(8))) __bf16 bf16x8;
typedef __attribute__((ext_vector_type(4))) __bf16 bf16x4;

#define L_SEQ 1024
#define NB 8
#define EMB 256
#define NHEAD 8
#define HD 32
#define MROWS 8192  // L_SEQ * NB
#define SZ_ELEM ((size_t)MROWS * EMB)

static __device__ __forceinline__ f32x4 mfma_bf16(bf16x8 a, bf16x8 b, f32x4 c) {
    return __builtin_amdgcn_mfma_f32_16x16x32_bf16(a, b, c, 0, 0, 0);
}
static __device__ __forceinline__ f32x16 mfma32(bf16x8 a, bf16x8 b, f32x16 c) {
    return __builtin_amdgcn_mfma_f32_32x32x16_bf16(a, b, c, 0, 0, 0);
}

// Scalar bf16 pack (PROVEN R1-R4/R6; do NOT replace with v_cvt_pk_bf16_f32 asm —
// R7 failed with it, suspected lo/hi element-order mismatch).
static __device__ __forceinline__ unsigned pack2(float a, float b) {
    union { __bf16 h; unsigned short u; } lo, hi;
    lo.h = (__bf16)a; hi.h = (__bf16)b;
    return (unsigned)lo.u | ((unsigned)hi.u << 16);
}

// v_permlane32_swap_b32: a.hi-half-lanes <-> b.lo-half-lanes (R4/R6-proven)
static __device__ __forceinline__ void permswap(unsigned &a, unsigned &b) {
    asm("v_permlane32_swap_b32 %0, %1" : "+v"(a), "+v"(b));
}

struct GemmBatch {
    const void* X[6];
    const float* W[6];
    const float* Bv[6];
    void* O[6];
    float scale[6];
};

// C[m,n] = (sum_k X[m,k] * W[n,k] + bias[n]) * scale
// BM=128, BN=64, BK=64, 256 threads = 4 waves (2x2), each wave 64x32.
// XMODE: 0 = f32 X, 1 = bf16 X.
template<int XMODE, bool OUT_F32>
__global__ __launch_bounds__(256, 2)
void gemm_kernel(GemmBatch batch) {
    __shared__ __bf16 Xl[128][72];
    __shared__ __bf16 Wl[64][72];
    const int z = blockIdx.z;
    const int fid = blockIdx.x;
    const int swz = (fid & 7) * 32 + (fid >> 3);   // 256 blocks -> 8 XCD chunks of 32
    const int nblk = swz & 3, mblk = swz >> 2;
    const float* __restrict__ W = batch.W[z];
    const float* __restrict__ bias = batch.Bv[z];
    const float scale = batch.scale[z];
    const int tid = threadIdx.x;
    const int w = tid >> 6, lane = tid & 63;
    const int g = lane >> 4, li = lane & 15;
    const int wr = w >> 1, wc = w & 1;

    f32x4 acc[4][2];
#pragma unroll
    for (int i = 0; i < 4; ++i)
#pragma unroll
        for (int j = 0; j < 2; ++j) acc[i][j] = f32x4{0.f, 0.f, 0.f, 0.f};

    for (int kk = 0; kk < 4; ++kk) {
        __syncthreads();
        if (XMODE == 1) {
            const __bf16* Xb = (const __bf16*)batch.X[z];
#pragma unroll
            for (int p = 0; p < 4; ++p) {
                int idx = tid + p * 256;
                int row = idx >> 3, c8 = (idx & 7) * 8;
                bf16x8 xv = *(const bf16x8*)(Xb + (size_t)(mblk * 128 + row) * 256 + kk * 64 + c8);
                *(bf16x8*)&Xl[row][c8] = xv;
            }
        } else {
            const float* Xf = (const float*)batch.X[z];
#pragma unroll
            for (int p = 0; p < 8; ++p) {
                int idx = tid + p * 256;
                int row = idx >> 4, c4 = (idx & 15) * 4;
                f32x4 xv = *(const f32x4*)(Xf + (size_t)(mblk * 128 + row) * 256 + kk * 64 + c4);
                bf16x4 bv;
#pragma unroll
                for (int j = 0; j < 4; ++j) bv[j] = (__bf16)xv[j];
                *(bf16x4*)&Xl[row][c4] = bv;
            }
        }
#pragma unroll
        for (int p = 0; p < 4; ++p) {
            int idx = tid + p * 256;
            int row = idx >> 4, c4 = (idx & 15) * 4;
            f32x4 wv = *(const f32x4*)(W + (size_t)(nblk * 64 + row) * 256 + kk * 64 + c4);
            bf16x4 bv;
#pragma unroll
            for (int j = 0; j < 4; ++j) bv[j] = (__bf16)wv[j];
            *(bf16x4*)&Wl[row][c4] = bv;
        }
        __syncthreads();
#pragma unroll
        for (int ks = 0; ks < 2; ++ks) {
            bf16x8 a[4], b[2];
#pragma unroll
            for (int af = 0; af < 4; ++af)
                a[af] = *(const bf16x8*)&Xl[wr * 64 + af * 16 + li][ks * 32 + g * 8];
#pragma unroll
            for (int bi = 0; bi < 2; ++bi)
                b[bi] = *(const bf16x8*)&Wl[wc * 32 + bi * 16 + li][ks * 32 + g * 8];
#pragma unroll
            for (int af = 0; af < 4; ++af)
#pragma unroll
                for (int bi = 0; bi < 2; ++bi)
                    acc[af][bi] = mfma_bf16(a[af], b[bi], acc[af][bi]);
        }
    }
#pragma unroll
    for (int af = 0; af < 4; ++af)
#pragma unroll
        for (int bi = 0; bi < 2; ++bi)
#pragma unroll
            for (int r = 0; r < 4; ++r) {
                int mrow = mblk * 128 + wr * 64 + af * 16 + 4 * g + r;
                int ncol = nblk * 64 + wc * 32 + bi * 16 + li;
                float v = (acc[af][bi][r] + bias[ncol]) * scale;
                if (OUT_F32)
                    ((float*)batch.O[z])[(size_t)mrow * 256 + ncol] = v;
                else
                    ((__bf16*)batch.O[z])[(size_t)mrow * 256 + ncol] = (__bf16)v;
            }
}

struct AttnArgs {
    const __bf16* Q[2];
    const __bf16* K[2];
    const __bf16* V[2];
    __bf16* AO[2];
};

// Swapped-QK^T flash attention, fixed-shift softmax (no online max).
// Q pre-scaled by (1/sqrt(hd))*log2(e); QK C-init = -12, p = exp2(s) via raw
// v_exp_f32 (this round's ONE isolated change vs the R4/R6-proven numerics).
// Row sums via MFMA with ones B-operand; epilogue shuffle-free.
// Grid: 1024 flat blocks XCD-swizzled; 256 threads = 4 waves, 32 q rows/wave.
__global__ __launch_bounds__(256, 4)
void attn_kernel(AttnArgs args) {
    __shared__ __bf16 Kl[128][40];   // K tile [s][d], padded
    __shared__ __bf16 Vt[32][136];   // V^T tile [d][s], padded + XOR-swizzled cols
    const int fid = blockIdx.x;
    const int swz = (fid & 7) * 128 + (fid >> 3);  // 1024 -> 8 XCD chunks of 128
    const int qb = swz & 7;
    const int nh = (swz >> 3) & 63;
    const int st = swz >> 9;
    const int n = nh >> 3, h = nh & 7;
    const __bf16* __restrict__ Q = args.Q[st];
    const __bf16* __restrict__ K = args.K[st];
    const __bf16* __restrict__ V = args.V[st];
    __bf16* __restrict__ AO = args.AO[st];
    const int tid = threadIdx.x;
    const int w = tid >> 6, lane = tid & 63;
    const int q32 = lane & 31, hi = lane >> 5;

    // Q B-fragments: col = q32, k(kb) = kb*16 + 8*hi + e
    bf16x8 qf[2];
    {
        int qrow = qb * 128 + w * 32 + q32;
#pragma unroll
        for (int kb = 0; kb < 2; ++kb)
            qf[kb] = *(const bf16x8*)(Q + ((size_t)qrow * NB + n) * EMB + h * HD + kb * 16 + hi * 8);
    }

    bf16x8 ones;
#pragma unroll
    for (int j = 0; j < 8; ++j) ones[j] = (__bf16)1.0f;

    f32x16 accO, accL;
#pragma unroll
    for (int r = 0; r < 16; ++r) { accO[r] = 0.f; accL[r] = 0.f; }

    const int vsw_r = ((q32 >> 3) & 3) << 3;   // read-side Vt column swizzle

    for (int t = 0; t < 8; ++t) {
        const int s0 = t * 128;
        __syncthreads();
#pragma unroll
        for (int p = 0; p < 2; ++p) {
            int idx = tid + p * 256;              // 0..511
            int row = idx >> 2, c8 = (idx & 3) * 8;
            size_t gaddr = ((size_t)(s0 + row) * NB + n) * EMB + h * HD + c8;
            *(bf16x8*)&Kl[row][c8] = *(const bf16x8*)(K + gaddr);
            bf16x8 vv = *(const bf16x8*)(V + gaddr);
#pragma unroll
            for (int j = 0; j < 8; ++j) {
                int d = c8 + j;
                Vt[d][row ^ (((d >> 3) & 3) << 3)] = vv[j];
            }
        }
        __syncthreads();

#pragma unroll
        for (int sb = 0; sb < 4; ++sb) {
            // S^T = K * Q^T - 12 : lane holds col q32, rows (r&3)+8*(r>>2)+4*hi
            bf16x8 kf0 = *(const bf16x8*)&Kl[sb * 32 + q32][hi * 8];
            bf16x8 kf1 = *(const bf16x8*)&Kl[sb * 32 + q32][16 + hi * 8];
            f32x16 s;
#pragma unroll
            for (int r = 0; r < 16; ++r) s[r] = -12.0f;   // fixed softmax shift
            __builtin_amdgcn_s_setprio(1);
            s = mfma32(kf0, qf[0], s);
            s = mfma32(kf1, qf[1], s);
            __builtin_amdgcn_s_setprio(0);
            float p[16];
#pragma unroll
            for (int r = 0; r < 16; ++r) p[r] = __builtin_amdgcn_exp2f(s[r]);

            // pack P -> bf16 A-fragments; half-swap via v_permlane32_swap_b32
            bf16x8 pa[2];
#pragma unroll
            for (int ks = 0; ks < 2; ++ks) {
                unsigned x0 = pack2(p[8 * ks + 0], p[8 * ks + 1]);
                unsigned x1 = pack2(p[8 * ks + 2], p[8 * ks + 3]);
                unsigned x2 = pack2(p[8 * ks + 4], p[8 * ks + 5]);
                unsigned x3 = pack2(p[8 * ks + 6], p[8 * ks + 7]);
                permswap(x0, x2);
                permswap(x1, x3);
                union { unsigned u[4]; bf16x8 v; } cvt;
                cvt.u[0] = x0; cvt.u[1] = x1; cvt.u[2] = x2; cvt.u[3] = x3;
                pa[ks] = cvt.v;
            }
            // PV and row-sum accumulation (both in C-layout, rows = q, cols = d)
            bf16x8 vf0 = *(const bf16x8*)&Vt[q32][(sb * 32 + hi * 8) ^ vsw_r];
            bf16x8 vf1 = *(const bf16x8*)&Vt[q32][(sb * 32 + 16 + hi * 8) ^ vsw_r];
            __builtin_amdgcn_s_setprio(1);
            accO = mfma32(pa[0], vf0, accO);
            accL = mfma32(pa[0], ones, accL);
            accO = mfma32(pa[1], vf1, accO);
            accL = mfma32(pa[1], ones, accL);
            __builtin_amdgcn_s_setprio(0);
        }
    }

    // epilogue: out = accO / accL (identical C-layout -> no shuffles)
#pragma unroll
    for (int r = 0; r < 16; ++r) {
        int crow = (r & 3) + 8 * (r >> 2) + 4 * hi;
        int row = qb * 128 + w * 32 + crow;
        AO[((size_t)row * NB + n) * EMB + h * HD + q32] = (__bf16)(accO[r] / accL[r]);
    }
}

extern "C" void kernel_launch(void* const* d_in, const int* in_sizes, int n_in,
                              void* d_out, int out_size, void* d_ws, size_t ws_size,
                              hipStream_t stream) {
    const size_t SZ = SZ_ELEM;
    __bf16* wsb = (__bf16*)d_ws;
    __bf16* arr[8];
    for (int i = 0; i < 8; ++i) arr[i] = wsb + (size_t)i * SZ;

    // 1/sqrt(32) * log2(e): fold attention scale + exp2 conversion into Q
    const float qscale = 0.25504310349362475f;

    GemmBatch pb{};
    for (int s = 0; s < 6; ++s) {
        pb.X[s] = d_in[s];
        pb.W[s] = (const float*)d_in[6 + s];
        pb.Bv[s] = (const float*)d_in[14 + s];
        pb.O[s] = arr[s];
        pb.scale[s] = (s == 0 || s == 3) ? qscale : 1.0f;
    }
    hipLaunchKernelGGL((gemm_kernel<0, false>), dim3(256, 1, 6), dim3(256), 0, stream, pb);

    AttnArgs aa{};
    aa.Q[0] = arr[0]; aa.K[0] = arr[1]; aa.V[0] = arr[2]; aa.AO[0] = arr[6];
    aa.Q[1] = arr[3]; aa.K[1] = arr[4]; aa.V[1] = arr[5]; aa.AO[1] = arr[7];
    hipLaunchKernelGGL(attn_kernel, dim3(1024), dim3(256), 0, stream, aa);

    GemmBatch ob{};
    for (int s = 0; s < 2; ++s) {
        ob.X[s] = arr[6 + s];
        ob.W[s] = (const float*)d_in[12 + s];
        ob.Bv[s] = (const float*)d_in[20 + s];
        ob.O[s] = (float*)d_out + (size_t)s * SZ;
        ob.scale[s] = 1.0f;
    }
    hipLaunchKernelGGL((gemm_kernel<1, true>), dim3(256, 1, 2), dim3(256), 0, stream, ob);
}